// Round 12
// baseline (206.150 us; speedup 1.0000x reference)
//
#include <hip/hip_runtime.h>
#include <math.h>

#define BB 8
#define NVV 2048
#define NPP 4096
#define DD 64
#define NQ (BB * NVV)     // 16384 vertex rows
#define QT (NQ / 16)      // 1024 query tiles
#define NC1 4             // key chunks KNN1 (64 tiles each)
#define NC2 2             // key chunks KNN2 (64 tiles each)

typedef __attribute__((ext_vector_type(8))) short short8;
typedef __attribute__((ext_vector_type(8))) unsigned short ushort8;
typedef __attribute__((ext_vector_type(4))) float f32x4;

// ws layout (float offsets), re-audited (R10 lesson: verify every stride):
// vm      @0        (16384)
// inv_vf_s@16384    (16384)   = 16384/norm (pre-scaled)
// inv_pf_s@32768    (32768)
// flow    @65536    (65536)
// pc1     @131072   (32*16384 = 524288 uints)
// pc2     @655360   (16*16384 = 262144 uints)
// qhi     @917504   (QT*1024 ushorts = 524288 floats)
// qlo     @1441792  (+524288)
// khi     @1966080  (2048*1024 ushorts = 1048576 floats)
// klo     @3014656  (+1048576)
// end     @4063232  floats = 16.3 MB

__device__ __forceinline__ unsigned short bf16rn(float x) {
  unsigned u = __float_as_uint(x);
  return (unsigned short)((u + 0x7FFFu + ((u >> 16) & 1u)) >> 16);
}
__device__ __forceinline__ float bf2f(unsigned short h) {
  return __uint_as_float(((unsigned)h) << 16);
}

// Branchless sorted-ascending top-8 insert: 7x v_med3_u32 + 1x max.
__device__ __forceinline__ void net8(unsigned* a, unsigned v) {
#pragma unroll
  for (int k = 0; k < 7; k++) {
    unsigned r;
    asm("v_med3_u32 %0, %1, %2, %3" : "=v"(r) : "v"(v), "v"(a[k]), "v"(a[k + 1]));
    a[k] = r;
  }
  a[7] = a[7] > v ? a[7] : v;
}

__device__ __forceinline__ void ins8(float* tv, int* ti, float v, int id) {
  bool c1 = v > tv[1], c2 = v > tv[2], c3 = v > tv[3];
  bool c4 = v > tv[4], c5 = v > tv[5], c6 = v > tv[6], c7 = v > tv[7];
  tv[0] = c1 ? tv[1] : v;                ti[0] = c1 ? ti[1] : id;
  tv[1] = c2 ? tv[2] : (c1 ? v : tv[1]); ti[1] = c2 ? ti[2] : (c1 ? id : ti[1]);
  tv[2] = c3 ? tv[3] : (c2 ? v : tv[2]); ti[2] = c3 ? ti[3] : (c2 ? id : ti[2]);
  tv[3] = c4 ? tv[4] : (c3 ? v : tv[3]); ti[3] = c4 ? ti[4] : (c3 ? id : ti[3]);
  tv[4] = c5 ? tv[5] : (c4 ? v : tv[4]); ti[4] = c5 ? ti[5] : (c4 ? id : ti[4]);
  tv[5] = c6 ? tv[6] : (c5 ? v : tv[5]); ti[5] = c6 ? ti[6] : (c5 ? id : ti[5]);
  tv[6] = c7 ? tv[7] : (c6 ? v : tv[6]); ti[6] = c7 ? ti[7] : (c6 ? id : ti[6]);
  tv[7] = c7 ? v : tv[7];                ti[7] = c7 ? id : ti[7];
}

// ===== kernel 1: vm (blocks 0..7) + inv-norms (next 3072) + bf16 frag staging =====
__global__ __launch_bounds__(256) void k_prep(const float* __restrict__ logits,
                                              const float* __restrict__ vf,
                                              const float* __restrict__ pf,
                                              float* __restrict__ vm,
                                              float* __restrict__ inv_vf_s,
                                              float* __restrict__ inv_pf_s,
                                              unsigned short* __restrict__ qhi,
                                              unsigned short* __restrict__ qlo,
                                              unsigned short* __restrict__ khi,
                                              unsigned short* __restrict__ klo,
                                              float* __restrict__ out) {
  int bid = blockIdx.x, t = threadIdx.x;
  if (bid < BB) {
    int b = bid;
    __shared__ float smn[4], smx[4];
    float vals[8];
    float mn = 1e30f, mx = -1e30f;
#pragma unroll
    for (int i = 0; i < 8; i++) {
      float x = logits[b * NVV + t + i * 256];
      float s = 1.0f / (1.0f + expf(-x));
      vals[i] = s;
      mn = fminf(mn, s);
      mx = fmaxf(mx, s);
    }
    for (int o = 32; o; o >>= 1) {
      mn = fminf(mn, __shfl_xor(mn, o, 64));
      mx = fmaxf(mx, __shfl_xor(mx, o, 64));
    }
    int w = t >> 6;
    if ((t & 63) == 0) { smn[w] = mn; smx[w] = mx; }
    __syncthreads();
    mn = fminf(fminf(smn[0], smn[1]), fminf(smn[2], smn[3]));
    mx = fmaxf(fmaxf(smx[0], smx[1]), fmaxf(smx[2], smx[3]));
    float range = mx - mn;
#pragma unroll
    for (int i = 0; i < 8; i++) {
      float v = (vals[i] - mn) / range;
      int g = b * NVV + t + i * 256;
      vm[g] = v;
      out[g * 4 + 3] = v;
    }
  } else if (bid < BB + 3072) {
    int T = (bid - BB) * 256 + t;
    int row = T >> 4, c = T & 15;
    const float* src;
    float* dst;
    int r;
    if (row < NQ) { src = vf; dst = inv_vf_s; r = row; }
    else { src = pf; dst = inv_pf_s; r = row - NQ; }
    float4 v = *(const float4*)(src + (size_t)r * DD + c * 4);
    float s = v.x * v.x + v.y * v.y + v.z * v.z + v.w * v.w;
#pragma unroll
    for (int m = 1; m <= 8; m <<= 1) s += __shfl_xor(s, m, 64);
    // pre-scaled by 16384: same mantissa as 1/norm (pow2 numerator), so
    // merge's s = dot * inv_s * 2^-14 is bit-identical to dot * (1/norm)
    if (c == 0) dst[r] = 16384.0f / fmaxf(sqrtf(s), 1e-12f);
  } else {
    // staging: one thread = one (tile,kk,lane) slot of 8 elems; hi/lo bf16 split
    int T = (bid - BB - 3072) * 256 + t;  // 0..393215
    const float* src;
    unsigned short *dh, *dl;
    int s;
    if (T < QT * 128) { s = T; src = vf; dh = qhi; dl = qlo; }
    else { s = T - QT * 128; src = pf; dh = khi; dl = klo; }
    int lane = s & 63, kk = (s >> 6) & 1, tile = s >> 7;
    size_t off = (size_t)(tile * 16 + (lane & 15)) * DD + kk * 32 + ((lane >> 4) & 3) * 8;
    float4 a = *(const float4*)(src + off);
    float4 b = *(const float4*)(src + off + 4);
    float xs[8] = {a.x, a.y, a.z, a.w, b.x, b.y, b.z, b.w};
    ushort8 h, l;
#pragma unroll
    for (int j = 0; j < 8; j++) {
      unsigned short hj = bf16rn(xs[j]);
      h[j] = hj;
      l[j] = bf16rn(xs[j] - bf2f(hj));
    }
    *(ushort8*)(dh + (size_t)s * 8) = h;
    *(ushort8*)(dl + (size_t)s * 8) = l;
  }
}

// ===== kernel 2: MFMA KNN candidate generation (fused KNN1 + KNN2) =====
// All waves uniform: 64 key tiles (R11: 2:1 wave imbalance -> tail, occ 34%).
// 6 MFMAs/tile (hi/lo bf16 split). Epilogue/key: add, fmaf(s2,iv_s,bias),
// max0, cvt, lshl_or, [mask cndmask], 8-op med3 net. pk=(u<<12)|key; u in
// [82k,443k] < 2^20. Merges re-rank candidates in exact fp32 (R6 lesson);
// mask is an explicit select (R9 lesson).
__global__ __launch_bounds__(256)
void k_knn(const unsigned short* __restrict__ qhi, const unsigned short* __restrict__ qlo,
           const unsigned short* __restrict__ khi, const unsigned short* __restrict__ klo,
           const float* __restrict__ inv_vf_s, const float* __restrict__ inv_pf_s,
           const float* __restrict__ vm,
           unsigned* __restrict__ pc1, unsigned* __restrict__ pc2) {
  int wid = (blockIdx.x * 256 + threadIdx.x) >> 6;
  int lane = threadIdx.x & 63, col = lane & 15, quad = lane >> 4;

  const unsigned short *BH, *BL;
  const float *inv, *mask;
  unsigned* PC;
  int qt_g, bt0, row0, ckb;
  if (wid < QT * NC1) {  // KNN1: keys = pf, 4 chunks x 64 tiles
    int ck = wid & (NC1 - 1);
    qt_g = wid >> 2;
    int batch = qt_g >> 7;
    BH = khi; BL = klo;
    inv = inv_pf_s + batch * NPP;
    mask = nullptr;
    bt0 = batch * 256 + ck * 64;
    PC = pc1;
    row0 = ck * 8; ckb = ck * 64;
  } else {               // KNN2: keys = vf, visible only, 2 chunks x 64 tiles
    int w = wid - QT * NC1;
    int ck = w & (NC2 - 1);
    qt_g = w >> 1;
    int batch = qt_g >> 7;
    BH = qhi; BL = qlo;
    inv = inv_vf_s + batch * NVV;
    mask = vm + batch * NVV;
    bt0 = batch * 128 + ck * 64;
    PC = pc2;
    row0 = ck * 8; ckb = ck * 64;
  }

  size_t ab = (size_t)qt_g * 1024 + lane * 8;
  short8 ah0 = *(const short8*)(qhi + ab);
  short8 ah1 = *(const short8*)(qhi + ab + 512);
  short8 al0 = *(const short8*)(qlo + ab);
  short8 al1 = *(const short8*)(qlo + ab + 512);

  unsigned tv[4][8];
#pragma unroll
  for (int r = 0; r < 4; r++)
#pragma unroll
    for (int k = 0; k < 8; k++) tv[r][k] = 0u;

#pragma unroll 2
  for (int kt = 0; kt < 64; kt++) {
    size_t bo = (size_t)(bt0 + kt) * 1024 + lane * 8;
    short8 bh0 = *(const short8*)(BH + bo);
    short8 bh1 = *(const short8*)(BH + bo + 512);
    short8 bl0 = *(const short8*)(BL + bo);
    short8 bl1 = *(const short8*)(BL + bo + 512);
    int key = (ckb + kt) * 16 + col;
    float iv = inv[key];
    bool ok = mask ? (mask[key] >= 0.5f) : true;
    f32x4 c0 = {0.f, 0.f, 0.f, 0.f}, c1 = {0.f, 0.f, 0.f, 0.f};
    c0 = __builtin_amdgcn_mfma_f32_16x16x32_bf16(ah0, bh0, c0, 0, 0, 0);
    c1 = __builtin_amdgcn_mfma_f32_16x16x32_bf16(ah1, bh1, c1, 0, 0, 0);
    c0 = __builtin_amdgcn_mfma_f32_16x16x32_bf16(ah0, bl0, c0, 0, 0, 0);
    c1 = __builtin_amdgcn_mfma_f32_16x16x32_bf16(ah1, bl1, c1, 0, 0, 0);
    c0 = __builtin_amdgcn_mfma_f32_16x16x32_bf16(al0, bh0, c0, 0, 0, 0);
    c1 = __builtin_amdgcn_mfma_f32_16x16x32_bf16(al1, bh1, c1, 0, 0, 0);
#pragma unroll
    for (int r = 0; r < 4; r++) {
      float s2 = c0[r] + c1[r];
      unsigned u = (unsigned)fmaxf(fmaf(s2, iv, 262144.0f), 0.0f);
      unsigned pk = (u << 12) | (unsigned)key;
      pk = ok ? pk : 0u;
      net8(tv[r], pk);
    }
  }

  // butterfly across the 16 cols (lane bits 0..3)
#pragma unroll
  for (int m = 1; m <= 8; m <<= 1) {
#pragma unroll
    for (int r = 0; r < 4; r++) {
      unsigned ov[8];
#pragma unroll
      for (int k = 0; k < 8; k++) ov[k] = (unsigned)__shfl_xor((int)tv[r][k], m, 64);
#pragma unroll
      for (int k = 7; k >= 0; k--) net8(tv[r], ov[k]);
    }
  }

  if (col == 0) {
#pragma unroll
    for (int r = 0; r < 4; r++) {
      int q = qt_g * 16 + quad * 4 + r;
#pragma unroll
      for (int k = 0; k < 8; k++)
        PC[(size_t)(row0 + k) * NQ + q] = tv[r][k];
    }
  }
}

__device__ __forceinline__ float dot64(const float4* __restrict__ a,
                                       const float4* __restrict__ b) {
  float a0 = 0.f, a1 = 0.f, a2 = 0.f, a3 = 0.f;
#pragma unroll
  for (int c = 0; c < 16; c++) {
    float4 x = a[c], y = b[c];
    a0 = fmaf(x.x, y.x, a0);
    a1 = fmaf(x.y, y.y, a1);
    a2 = fmaf(x.z, y.z, a2);
    a3 = fmaf(x.w, y.w, a3);
  }
  return (a0 + a1) + (a2 + a3);
}

// ===== kernel 3: exact re-rank of 32 KNN1 candidates + flow_init (32 lanes/q) =====
// Weight = s_exact * 16384 / inv_s[id]  (no second dot64 -- R12 trim).
__global__ __launch_bounds__(256) void k_merge_flow(const unsigned* __restrict__ pc,
                                                    const float* __restrict__ vf,
                                                    const float* __restrict__ pf,
                                                    const float* __restrict__ pts,
                                                    const float* __restrict__ vtx,
                                                    const float* __restrict__ inv_pf_s,
                                                    float* __restrict__ flow_ws,
                                                    float* __restrict__ out) {
  int T = blockIdx.x * 256 + threadIdx.x;
  int q = T >> 5, c = T & 31, batch = q >> 11;
  const float4* qp = (const float4*)(vf + (size_t)q * DD);
  float tv[8];
  int ti[8];
#pragma unroll
  for (int k = 0; k < 8; k++) { tv[k] = -3.0e38f; ti[k] = 0; }
  {  // 32 candidate rows / 32 lanes (KNN1 pk always valid: u >= 82k)
    unsigned pk = pc[(size_t)c * NQ + q];
    int id = (int)(pk & 0xFFFu);
    int prow = batch * NPP + id;
    float s = dot64(qp, (const float4*)(pf + (size_t)prow * DD)) *
              inv_pf_s[prow] * 6.103515625e-5f;  // * 2^-14
    ins8(tv, ti, s, id);
  }
#pragma unroll
  for (int m = 1; m <= 16; m <<= 1) {  // butterfly within the 32-lane group
    float ov[8];
    int oi[8];
#pragma unroll
    for (int k = 0; k < 8; k++) {
      ov[k] = __shfl_xor(tv[k], m, 64);
      oi[k] = __shfl_xor(ti[k], m, 64);
    }
#pragma unroll
    for (int k = 7; k >= 0; k--)
      if (ov[k] > tv[0]) ins8(tv, ti, ov[k], oi[k]);
  }
  int id = ti[0];
  float sv = tv[0];
#pragma unroll
  for (int k = 1; k < 8; k++) {
    id = (c == k) ? ti[k] : id;
    sv = (c == k) ? tv[k] : sv;
  }

  float ax = 0.f, ay = 0.f, az = 0.f, den = 0.f;
  if (c < 8) {
    int prow = batch * NPP + id;
    float w = sv * 16384.0f / inv_pf_s[prow];  // = raw dot (exact ratio)
    ax = (pts[prow * 3 + 0] - vtx[q * 3 + 0]) * w;
    ay = (pts[prow * 3 + 1] - vtx[q * 3 + 1]) * w;
    az = (pts[prow * 3 + 2] - vtx[q * 3 + 2]) * w;
    den = w;
  }
#pragma unroll
  for (int m = 1; m <= 16; m <<= 1) {
    ax += __shfl_xor(ax, m, 64);
    ay += __shfl_xor(ay, m, 64);
    az += __shfl_xor(az, m, 64);
    den += __shfl_xor(den, m, 64);
  }
  if (c == 0) {
    float fx = ax / den, fy = ay / den, fz = az / den;
    flow_ws[q * 4 + 0] = fx;
    flow_ws[q * 4 + 1] = fy;
    flow_ws[q * 4 + 2] = fz;
    out[q * 4 + 0] = fx;
    out[q * 4 + 1] = fy;
    out[q * 4 + 2] = fz;
  }
}

// ===== kernel 4: exact re-rank of 16 KNN2 candidates + interpolate invisible =====
__global__ __launch_bounds__(256) void k_merge_final(const unsigned* __restrict__ pc,
                                                     const float* __restrict__ vf,
                                                     const float* __restrict__ vm,
                                                     const float* __restrict__ inv_vf_s,
                                                     const float* __restrict__ flow_ws,
                                                     float* __restrict__ out) {
  int T = blockIdx.x * 256 + threadIdx.x;
  int q = T >> 4, c = T & 15, batch = q >> 11;
  if (vm[q] >= 0.5f) return;
  const float4* qp = (const float4*)(vf + (size_t)q * DD);
  float tv[8];
  int ti[8];
#pragma unroll
  for (int k = 0; k < 8; k++) { tv[k] = -3.0e38f; ti[k] = 0; }
  {  // 16 candidate rows / 16 lanes; pk <= 0xFFF = masked sentinel, skip
    unsigned pk = pc[(size_t)c * NQ + q];
    if (pk > 0xFFFu) {
      int id = (int)(pk & 0xFFFu);
      int krow = batch * NVV + id;
      float s = dot64(qp, (const float4*)(vf + (size_t)krow * DD)) *
                inv_vf_s[krow] * 6.103515625e-5f;
      ins8(tv, ti, s, id);
    }
  }
#pragma unroll
  for (int m = 1; m <= 8; m <<= 1) {
    float ov[8];
    int oi[8];
#pragma unroll
    for (int k = 0; k < 8; k++) {
      ov[k] = __shfl_xor(tv[k], m, 64);
      oi[k] = __shfl_xor(ti[k], m, 64);
    }
#pragma unroll
    for (int k = 7; k >= 0; k--)
      if (ov[k] > tv[0]) ins8(tv, ti, ov[k], oi[k]);
  }
  int id = ti[0];
  float sv = tv[0];
#pragma unroll
  for (int k = 1; k < 8; k++) {
    id = (c == k) ? ti[k] : id;
    sv = (c == k) ? tv[k] : sv;
  }

  float ax = 0.f, ay = 0.f, az = 0.f, den = 0.f;
  if (c < 8) {
    int krow = batch * NVV + id;
    float w = sv * 16384.0f / inv_vf_s[krow];
    ax = flow_ws[krow * 4 + 0] * w;
    ay = flow_ws[krow * 4 + 1] * w;
    az = flow_ws[krow * 4 + 2] * w;
    den = w;
  }
#pragma unroll
  for (int m = 1; m <= 8; m <<= 1) {
    ax += __shfl_xor(ax, m, 64);
    ay += __shfl_xor(ay, m, 64);
    az += __shfl_xor(az, m, 64);
    den += __shfl_xor(den, m, 64);
  }
  if (c == 0) {
    out[q * 4 + 0] = ax / den;
    out[q * 4 + 1] = ay / den;
    out[q * 4 + 2] = az / den;
  }
}

extern "C" void kernel_launch(void* const* d_in, const int* in_sizes, int n_in,
                              void* d_out, int out_size, void* d_ws, size_t ws_size,
                              hipStream_t stream) {
  const float* vtx = (const float*)d_in[0];
  const float* pts = (const float*)d_in[1];
  const float* vf = (const float*)d_in[2];
  const float* pf = (const float*)d_in[3];
  const float* lg = (const float*)d_in[4];
  float* out = (float*)d_out;
  float* ws = (float*)d_ws;

  float* vm = ws;
  float* inv_vf_s = ws + 16384;
  float* inv_pf_s = ws + 32768;
  float* flow = ws + 65536;
  unsigned* pc1 = (unsigned*)(ws + 131072);                // 32 rows
  unsigned* pc2 = (unsigned*)(ws + 655360);                // 16 rows
  unsigned short* qhi = (unsigned short*)(ws + 917504);
  unsigned short* qlo = (unsigned short*)(ws + 1441792);   // qhi + 524288 floats
  unsigned short* khi = (unsigned short*)(ws + 1966080);   // qlo + 524288
  unsigned short* klo = (unsigned short*)(ws + 3014656);   // khi + 1048576

  k_prep<<<BB + 3072 + 1536, 256, 0, stream>>>(lg, vf, pf, vm, inv_vf_s, inv_pf_s,
                                               qhi, qlo, khi, klo, out);
  k_knn<<<(QT * NC1 + QT * NC2) / 4, 256, 0, stream>>>(qhi, qlo, khi, klo,
                                                       inv_vf_s, inv_pf_s, vm, pc1, pc2);
  k_merge_flow<<<NQ * 32 / 256, 256, 0, stream>>>(pc1, vf, pf, pts, vtx,
                                                  inv_pf_s, flow, out);
  k_merge_final<<<NQ * 16 / 256, 256, 0, stream>>>(pc2, vf, vm, inv_vf_s, flow, out);
}

// Round 13
// 201.185 us; speedup vs baseline: 1.0247x; 1.0247x over previous
//
#include <hip/hip_runtime.h>
#include <math.h>

#define BB 8
#define NVV 2048
#define NPP 4096
#define DD 64
#define NQ (BB * NVV)     // 16384 vertex rows
#define QT (NQ / 16)      // 1024 query tiles
#define NC1 4             // key chunks KNN1 (64 tiles each)
#define NC2 2             // key chunks KNN2 (64 tiles each)

typedef __attribute__((ext_vector_type(8))) short short8;
typedef __attribute__((ext_vector_type(8))) unsigned short ushort8;
typedef __attribute__((ext_vector_type(4))) float f32x4;

// ws layout (float offsets), audited line-by-line (R10 lesson):
// vm      @0        (16384)
// inv_vf_s@16384    (16384)   = 16384/norm (written by staging)
// inv_pf_s@32768    (32768)
// flow    @65536    (65536)
// pc1     @131072   (32*16384 uints = 524288)
// pc2     @655360   (16*16384 uints = 262144)
// vfh     @917504   (QT*1024 ushorts = 524288 floats)  normalized vf frags hi
// vfl     @1441792  (+524288)                          normalized vf frags lo
// pfh     @1966080  (2048*1024 ushorts = 1048576 floats)
// pfl     @3014656  (+1048576)
// end     @4063232  floats = 16.25 MB

__device__ __forceinline__ unsigned short bf16rn(float x) {
  unsigned u = __float_as_uint(x);
  return (unsigned short)((u + 0x7FFFu + ((u >> 16) & 1u)) >> 16);
}
__device__ __forceinline__ float bf2f(unsigned short h) {
  return __uint_as_float(((unsigned)h) << 16);
}

// Branchless sorted-ascending top-8 insert: 7x v_med3_u32 + 1x max.
__device__ __forceinline__ void net8(unsigned* a, unsigned v) {
#pragma unroll
  for (int k = 0; k < 7; k++) {
    unsigned r;
    asm("v_med3_u32 %0, %1, %2, %3" : "=v"(r) : "v"(v), "v"(a[k]), "v"(a[k + 1]));
    a[k] = r;
  }
  a[7] = a[7] > v ? a[7] : v;
}

__device__ __forceinline__ void ins8(float* tv, int* ti, float v, int id) {
  bool c1 = v > tv[1], c2 = v > tv[2], c3 = v > tv[3];
  bool c4 = v > tv[4], c5 = v > tv[5], c6 = v > tv[6], c7 = v > tv[7];
  tv[0] = c1 ? tv[1] : v;                ti[0] = c1 ? ti[1] : id;
  tv[1] = c2 ? tv[2] : (c1 ? v : tv[1]); ti[1] = c2 ? ti[2] : (c1 ? id : ti[1]);
  tv[2] = c3 ? tv[3] : (c2 ? v : tv[2]); ti[2] = c3 ? ti[3] : (c2 ? id : ti[2]);
  tv[3] = c4 ? tv[4] : (c3 ? v : tv[3]); ti[3] = c4 ? ti[4] : (c3 ? id : ti[3]);
  tv[4] = c5 ? tv[5] : (c4 ? v : tv[4]); ti[4] = c5 ? ti[5] : (c4 ? id : ti[4]);
  tv[5] = c6 ? tv[6] : (c5 ? v : tv[5]); ti[5] = c6 ? ti[6] : (c5 ? id : ti[5]);
  tv[6] = c7 ? tv[7] : (c6 ? v : tv[6]); ti[6] = c7 ? ti[7] : (c6 ? id : ti[6]);
  tv[7] = c7 ? v : tv[7];                ti[7] = c7 ? id : ti[7];
}

// ===== kernel 1: vm (blocks 0..7) + fused norm+normalize+bf16 staging =====
// Staging block = 256 threads = 2 tiles. Each tile's 128 threads compute row
// sumsq partials in LDS, reduce to 16 row norms, write inv_s arrays, then
// normalize and hi/lo-split. Normalized keys make sims cosines -> no per-tile
// inv load in k_knn (ranking unaffected: merges re-rank exact fp32).
__global__ __launch_bounds__(256) void k_prep(const float* __restrict__ logits,
                                              const float* __restrict__ vf,
                                              const float* __restrict__ pf,
                                              float* __restrict__ vm,
                                              float* __restrict__ inv_vf_s,
                                              float* __restrict__ inv_pf_s,
                                              unsigned short* __restrict__ vfh,
                                              unsigned short* __restrict__ vfl,
                                              unsigned short* __restrict__ pfh,
                                              unsigned short* __restrict__ pfl,
                                              float* __restrict__ out) {
  __shared__ float smn[4], smx[4];
  __shared__ float part[256];
  __shared__ float sinv[32];
  int bid = blockIdx.x, t = threadIdx.x;
  if (bid < BB) {
    int b = bid;
    float vals[8];
    float mn = 1e30f, mx = -1e30f;
#pragma unroll
    for (int i = 0; i < 8; i++) {
      float x = logits[b * NVV + t + i * 256];
      float s = 1.0f / (1.0f + expf(-x));
      vals[i] = s;
      mn = fminf(mn, s);
      mx = fmaxf(mx, s);
    }
    for (int o = 32; o; o >>= 1) {
      mn = fminf(mn, __shfl_xor(mn, o, 64));
      mx = fmaxf(mx, __shfl_xor(mx, o, 64));
    }
    int w = t >> 6;
    if ((t & 63) == 0) { smn[w] = mn; smx[w] = mx; }
    __syncthreads();
    mn = fminf(fminf(smn[0], smn[1]), fminf(smn[2], smn[3]));
    mx = fmaxf(fmaxf(smx[0], smx[1]), fmaxf(smx[2], smx[3]));
    float range = mx - mn;
#pragma unroll
    for (int i = 0; i < 8; i++) {
      float v = (vals[i] - mn) / range;
      int g = b * NVV + t + i * 256;
      vm[g] = v;
      out[g * 4 + 3] = v;
    }
  } else {
    // staging: slot s = one (tile, kk, lane); blocks never straddle the
    // vf/pf boundary (131072 % 256 == 0)
    int T = (bid - BB) * 256 + t;  // 0..393215
    const float* src;
    unsigned short *dh, *dl;
    float* ginv;
    int s;
    if (T < QT * 128) { s = T; src = vf; dh = vfh; dl = vfl; ginv = inv_vf_s; }
    else { s = T - QT * 128; src = pf; dh = pfh; dl = pfl; ginv = inv_pf_s; }
    int lane = t & 63, kk = (t >> 6) & 1, tl = t >> 7;   // block-local == slot-local
    int tile = s >> 7;
    int c = lane & 15, quad = (lane >> 4) & 3;
    int row = tile * 16 + c;
    size_t off = (size_t)row * DD + kk * 32 + quad * 8;
    float4 a = *(const float4*)(src + off);
    float4 b = *(const float4*)(src + off + 4);
    float xs[8] = {a.x, a.y, a.z, a.w, b.x, b.y, b.z, b.w};
    float ss = 0.f;
#pragma unroll
    for (int j = 0; j < 8; j++) ss = fmaf(xs[j], xs[j], ss);
    part[t] = ss;
    __syncthreads();
    if ((t & 127) < 16) {  // kk==0, quad==0: aggregate row c of tile tl
      float tot = 0.f;
#pragma unroll
      for (int u = 0; u < 8; u++)
        tot += part[tl * 128 + (u >> 2) * 64 + (u & 3) * 16 + c];
      float inv = 1.0f / fmaxf(sqrtf(tot), 1e-12f);
      sinv[tl * 16 + c] = inv;
      ginv[row] = 16384.0f * inv;  // pow2 scale: merge's *2^-14 is exact
    }
    __syncthreads();
    float inv = sinv[tl * 16 + c];
    ushort8 h, l;
#pragma unroll
    for (int j = 0; j < 8; j++) {
      float xn = xs[j] * inv;
      unsigned short hj = bf16rn(xn);
      h[j] = hj;
      l[j] = bf16rn(xn - bf2f(hj));
    }
    *(ushort8*)(dh + (size_t)s * 8) = h;
    *(ushort8*)(dl + (size_t)s * 8) = l;
  }
}

// ===== kernel 2: MFMA KNN candidate generation (fused KNN1 + KNN2) =====
// TRANSPOSED (R12 lesson: 4 top-8 lists/lane = 32 regs -> AGPR parking +
// shuttle): A = key tiles, B = query frags -> C[key][query]; each lane owns
// ONE query (col=lane&15) and inserts its 4 key-elems into a single tv[8].
// Keys pre-normalized -> sims are cosines, no inv load. pk =
// ((uint)(s*520000+520000) << 12) | key  (u < 2^20; quantization ~2e-6 --
// candidate superset only, merges re-rank exact fp32 per R6). Mask is an
// explicit per-key select (R9 lesson). Butterfly: 2 rounds (quad bits).
__global__ __launch_bounds__(256)
void k_knn(const unsigned short* __restrict__ vfh, const unsigned short* __restrict__ vfl,
           const unsigned short* __restrict__ pfh, const unsigned short* __restrict__ pfl,
           const float* __restrict__ vm,
           unsigned* __restrict__ pc1, unsigned* __restrict__ pc2) {
  int wid = (blockIdx.x * 256 + threadIdx.x) >> 6;
  int lane = threadIdx.x & 63, col = lane & 15, quad = lane >> 4;

  const unsigned short *KH, *KL;
  const float* mask;
  unsigned* PC;
  int qt_g, bt0, row0, ckb;
  if (wid < QT * NC1) {  // KNN1: keys = pf
    int ck = wid & (NC1 - 1);
    qt_g = wid >> 2;
    int batch = qt_g >> 7;
    KH = pfh; KL = pfl;
    mask = nullptr;
    bt0 = batch * 256 + ck * 64;
    PC = pc1;
    row0 = ck * 8; ckb = ck * 64;
  } else {               // KNN2: keys = vf (normalized frags), visible only
    int w = wid - QT * NC1;
    int ck = w & (NC2 - 1);
    qt_g = w >> 1;
    int batch = qt_g >> 7;
    KH = vfh; KL = vfl;
    mask = vm + batch * NVV;
    bt0 = batch * 128 + ck * 64;
    PC = pc2;
    row0 = ck * 8; ckb = ck * 64;
  }

  size_t ab = (size_t)qt_g * 1024 + lane * 8;
  short8 qh0 = *(const short8*)(vfh + ab);
  short8 qh1 = *(const short8*)(vfh + ab + 512);
  short8 ql0 = *(const short8*)(vfl + ab);
  short8 ql1 = *(const short8*)(vfl + ab + 512);

  unsigned tv[8];
#pragma unroll
  for (int k = 0; k < 8; k++) tv[k] = 0u;

#pragma unroll 2
  for (int kt = 0; kt < 64; kt++) {
    size_t bo = (size_t)(bt0 + kt) * 1024 + lane * 8;
    short8 kh0 = *(const short8*)(KH + bo);
    short8 kh1 = *(const short8*)(KH + bo + 512);
    short8 kl0 = *(const short8*)(KL + bo);
    short8 kl1 = *(const short8*)(KL + bo + 512);
    int base16 = (ckb + kt) * 16;
    f32x4 c0 = {0.f, 0.f, 0.f, 0.f}, c1 = {0.f, 0.f, 0.f, 0.f};
    c0 = __builtin_amdgcn_mfma_f32_16x16x32_bf16(kh0, qh0, c0, 0, 0, 0);
    c1 = __builtin_amdgcn_mfma_f32_16x16x32_bf16(kh1, qh1, c1, 0, 0, 0);
    c0 = __builtin_amdgcn_mfma_f32_16x16x32_bf16(kh0, ql0, c0, 0, 0, 0);
    c1 = __builtin_amdgcn_mfma_f32_16x16x32_bf16(kh1, ql1, c1, 0, 0, 0);
    c0 = __builtin_amdgcn_mfma_f32_16x16x32_bf16(kl0, qh0, c0, 0, 0, 0);
    c1 = __builtin_amdgcn_mfma_f32_16x16x32_bf16(kl1, qh1, c1, 0, 0, 0);
    float4 mv;
    if (mask) mv = *(const float4*)(mask + base16 + quad * 4);
#pragma unroll
    for (int r = 0; r < 4; r++) {
      float s2 = c0[r] + c1[r];
      unsigned u = (unsigned)fmaxf(fmaf(s2, 520000.0f, 520000.0f), 0.0f);
      unsigned pk = (u << 12) | (unsigned)(base16 + quad * 4 + r);
      if (mask) {
        float mr = (r == 0) ? mv.x : (r == 1) ? mv.y : (r == 2) ? mv.z : mv.w;
        pk = (mr >= 0.5f) ? pk : 0u;
      }
      net8(tv, pk);
    }
  }

  // butterfly across the 4 quads (lane bits 4,5): all quads -> same top-8
#pragma unroll
  for (int m = 16; m <= 32; m <<= 1) {
    unsigned ov[8];
#pragma unroll
    for (int k = 0; k < 8; k++) ov[k] = (unsigned)__shfl_xor((int)tv[k], m, 64);
#pragma unroll
    for (int k = 7; k >= 0; k--) net8(tv, ov[k]);
  }

  if (quad == 0) {
    int q = qt_g * 16 + col;
#pragma unroll
    for (int k = 0; k < 8; k++)
      PC[(size_t)(row0 + k) * NQ + q] = tv[k];
  }
}

__device__ __forceinline__ float dot64(const float4* __restrict__ a,
                                       const float4* __restrict__ b) {
  float a0 = 0.f, a1 = 0.f, a2 = 0.f, a3 = 0.f;
#pragma unroll
  for (int c = 0; c < 16; c++) {
    float4 x = a[c], y = b[c];
    a0 = fmaf(x.x, y.x, a0);
    a1 = fmaf(x.y, y.y, a1);
    a2 = fmaf(x.z, y.z, a2);
    a3 = fmaf(x.w, y.w, a3);
  }
  return (a0 + a1) + (a2 + a3);
}

// ===== kernel 3: exact re-rank of 32 KNN1 candidates + flow_init (32 lanes/q) =====
__global__ __launch_bounds__(256) void k_merge_flow(const unsigned* __restrict__ pc,
                                                    const float* __restrict__ vf,
                                                    const float* __restrict__ pf,
                                                    const float* __restrict__ pts,
                                                    const float* __restrict__ vtx,
                                                    const float* __restrict__ inv_pf_s,
                                                    float* __restrict__ flow_ws,
                                                    float* __restrict__ out) {
  int T = blockIdx.x * 256 + threadIdx.x;
  int q = T >> 5, c = T & 31, batch = q >> 11;
  const float4* qp = (const float4*)(vf + (size_t)q * DD);
  float tv[8];
  int ti[8];
#pragma unroll
  for (int k = 0; k < 8; k++) { tv[k] = -3.0e38f; ti[k] = 0; }
  {  // 32 candidate rows / 32 lanes
    unsigned pk = pc[(size_t)c * NQ + q];
    int id = (int)(pk & 0xFFFu);
    int prow = batch * NPP + id;
    float s = dot64(qp, (const float4*)(pf + (size_t)prow * DD)) *
              inv_pf_s[prow] * 6.103515625e-5f;  // * 2^-14
    ins8(tv, ti, s, id);
  }
#pragma unroll
  for (int m = 1; m <= 16; m <<= 1) {
    float ov[8];
    int oi[8];
#pragma unroll
    for (int k = 0; k < 8; k++) {
      ov[k] = __shfl_xor(tv[k], m, 64);
      oi[k] = __shfl_xor(ti[k], m, 64);
    }
#pragma unroll
    for (int k = 7; k >= 0; k--)
      if (ov[k] > tv[0]) ins8(tv, ti, ov[k], oi[k]);
  }
  int id = ti[0];
  float sv = tv[0];
#pragma unroll
  for (int k = 1; k < 8; k++) {
    id = (c == k) ? ti[k] : id;
    sv = (c == k) ? tv[k] : sv;
  }

  float ax = 0.f, ay = 0.f, az = 0.f, den = 0.f;
  if (c < 8) {
    int prow = batch * NPP + id;
    float w = sv * 16384.0f / inv_pf_s[prow];  // = raw dot (exact pow2 ratio)
    ax = (pts[prow * 3 + 0] - vtx[q * 3 + 0]) * w;
    ay = (pts[prow * 3 + 1] - vtx[q * 3 + 1]) * w;
    az = (pts[prow * 3 + 2] - vtx[q * 3 + 2]) * w;
    den = w;
  }
#pragma unroll
  for (int m = 1; m <= 16; m <<= 1) {
    ax += __shfl_xor(ax, m, 64);
    ay += __shfl_xor(ay, m, 64);
    az += __shfl_xor(az, m, 64);
    den += __shfl_xor(den, m, 64);
  }
  if (c == 0) {
    float fx = ax / den, fy = ay / den, fz = az / den;
    flow_ws[q * 4 + 0] = fx;
    flow_ws[q * 4 + 1] = fy;
    flow_ws[q * 4 + 2] = fz;
    out[q * 4 + 0] = fx;
    out[q * 4 + 1] = fy;
    out[q * 4 + 2] = fz;
  }
}

// ===== kernel 4: exact re-rank of 16 KNN2 candidates + interpolate invisible =====
__global__ __launch_bounds__(256) void k_merge_final(const unsigned* __restrict__ pc,
                                                     const float* __restrict__ vf,
                                                     const float* __restrict__ vm,
                                                     const float* __restrict__ inv_vf_s,
                                                     const float* __restrict__ flow_ws,
                                                     float* __restrict__ out) {
  int T = blockIdx.x * 256 + threadIdx.x;
  int q = T >> 4, c = T & 15, batch = q >> 11;
  if (vm[q] >= 0.5f) return;
  const float4* qp = (const float4*)(vf + (size_t)q * DD);
  float tv[8];
  int ti[8];
#pragma unroll
  for (int k = 0; k < 8; k++) { tv[k] = -3.0e38f; ti[k] = 0; }
  {  // 16 candidate rows / 16 lanes; pk <= 0xFFF = masked sentinel, skip
    unsigned pk = pc[(size_t)c * NQ + q];
    if (pk > 0xFFFu) {
      int id = (int)(pk & 0xFFFu);
      int krow = batch * NVV + id;
      float s = dot64(qp, (const float4*)(vf + (size_t)krow * DD)) *
                inv_vf_s[krow] * 6.103515625e-5f;
      ins8(tv, ti, s, id);
    }
  }
#pragma unroll
  for (int m = 1; m <= 8; m <<= 1) {
    float ov[8];
    int oi[8];
#pragma unroll
    for (int k = 0; k < 8; k++) {
      ov[k] = __shfl_xor(tv[k], m, 64);
      oi[k] = __shfl_xor(ti[k], m, 64);
    }
#pragma unroll
    for (int k = 7; k >= 0; k--)
      if (ov[k] > tv[0]) ins8(tv, ti, ov[k], oi[k]);
  }
  int id = ti[0];
  float sv = tv[0];
#pragma unroll
  for (int k = 1; k < 8; k++) {
    id = (c == k) ? ti[k] : id;
    sv = (c == k) ? tv[k] : sv;
  }

  float ax = 0.f, ay = 0.f, az = 0.f, den = 0.f;
  if (c < 8) {
    int krow = batch * NVV + id;
    float w = sv * 16384.0f / inv_vf_s[krow];
    ax = flow_ws[krow * 4 + 0] * w;
    ay = flow_ws[krow * 4 + 1] * w;
    az = flow_ws[krow * 4 + 2] * w;
    den = w;
  }
#pragma unroll
  for (int m = 1; m <= 8; m <<= 1) {
    ax += __shfl_xor(ax, m, 64);
    ay += __shfl_xor(ay, m, 64);
    az += __shfl_xor(az, m, 64);
    den += __shfl_xor(den, m, 64);
  }
  if (c == 0) {
    out[q * 4 + 0] = ax / den;
    out[q * 4 + 1] = ay / den;
    out[q * 4 + 2] = az / den;
  }
}

extern "C" void kernel_launch(void* const* d_in, const int* in_sizes, int n_in,
                              void* d_out, int out_size, void* d_ws, size_t ws_size,
                              hipStream_t stream) {
  const float* vtx = (const float*)d_in[0];
  const float* pts = (const float*)d_in[1];
  const float* vf = (const float*)d_in[2];
  const float* pf = (const float*)d_in[3];
  const float* lg = (const float*)d_in[4];
  float* out = (float*)d_out;
  float* ws = (float*)d_ws;

  float* vm = ws;
  float* inv_vf_s = ws + 16384;
  float* inv_pf_s = ws + 32768;
  float* flow = ws + 65536;
  unsigned* pc1 = (unsigned*)(ws + 131072);
  unsigned* pc2 = (unsigned*)(ws + 655360);
  unsigned short* vfh = (unsigned short*)(ws + 917504);
  unsigned short* vfl = (unsigned short*)(ws + 1441792);   // +524288 floats
  unsigned short* pfh = (unsigned short*)(ws + 1966080);   // +524288
  unsigned short* pfl = (unsigned short*)(ws + 3014656);   // +1048576

  k_prep<<<BB + 1536, 256, 0, stream>>>(lg, vf, pf, vm, inv_vf_s, inv_pf_s,
                                        vfh, vfl, pfh, pfl, out);
  k_knn<<<(QT * NC1 + QT * NC2) / 4, 256, 0, stream>>>(vfh, vfl, pfh, pfl,
                                                       vm, pc1, pc2);
  k_merge_flow<<<NQ * 32 / 256, 256, 0, stream>>>(pc1, vf, pf, pts, vtx,
                                                  inv_pf_s, flow, out);
  k_merge_final<<<NQ * 16 / 256, 256, 0, stream>>>(pc2, vf, vm, inv_vf_s, flow, out);
}

// Round 14
// 179.794 us; speedup vs baseline: 1.1466x; 1.1190x over previous
//
#include <hip/hip_runtime.h>
#include <math.h>

#define BB 8
#define NVV 2048
#define NPP 4096
#define DD 64
#define NQ (BB * NVV)     // 16384 vertex rows
#define QT (NQ / 16)      // 1024 query tiles
#define NC1 2             // key chunks KNN1 (128 tiles each)
#define NC2 2             // key chunks KNN2 (64 tiles each)

typedef __attribute__((ext_vector_type(8))) short short8;
typedef __attribute__((ext_vector_type(8))) unsigned short ushort8;
typedef __attribute__((ext_vector_type(4))) float f32x4;

// ws layout (float offsets), audited line-by-line (R10 lesson):
// vm      @0        (16384)
// inv_vf_s@16384    (16384)   = 16384/norm
// inv_pf_s@32768    (32768)
// flow    @65536    (65536)
// pc1     @131072   (16*16384 uints = 262144)
// pc2     @393216   (16*16384 uints = 262144)
// vfh     @655360   (QT*1024 ushorts = 524288 floats)
// vfl     @1179648  (+524288)
// pfh     @1703936  (2048 tiles*1024 ushorts = 1048576 floats)
// pfl     @2752512  (+1048576)
// end     @3801088  floats = 14.5 MB

__device__ __forceinline__ unsigned short bf16rn(float x) {
  unsigned u = __float_as_uint(x);
  return (unsigned short)((u + 0x7FFFu + ((u >> 16) & 1u)) >> 16);
}
__device__ __forceinline__ float bf2f(unsigned short h) {
  return __uint_as_float(((unsigned)h) << 16);
}

// Branchless sorted-ascending top-8 insert: 7x v_med3_u32 + 1x max.
__device__ __forceinline__ void net8(unsigned* a, unsigned v) {
#pragma unroll
  for (int k = 0; k < 7; k++) {
    unsigned r;
    asm("v_med3_u32 %0, %1, %2, %3" : "=v"(r) : "v"(v), "v"(a[k]), "v"(a[k + 1]));
    a[k] = r;
  }
  a[7] = a[7] > v ? a[7] : v;
}

__device__ __forceinline__ void ins8(float* tv, int* ti, float v, int id) {
  bool c1 = v > tv[1], c2 = v > tv[2], c3 = v > tv[3];
  bool c4 = v > tv[4], c5 = v > tv[5], c6 = v > tv[6], c7 = v > tv[7];
  tv[0] = c1 ? tv[1] : v;                ti[0] = c1 ? ti[1] : id;
  tv[1] = c2 ? tv[2] : (c1 ? v : tv[1]); ti[1] = c2 ? ti[2] : (c1 ? id : ti[1]);
  tv[2] = c3 ? tv[3] : (c2 ? v : tv[2]); ti[2] = c3 ? ti[3] : (c2 ? id : ti[2]);
  tv[3] = c4 ? tv[4] : (c3 ? v : tv[3]); ti[3] = c4 ? ti[4] : (c3 ? id : ti[3]);
  tv[4] = c5 ? tv[5] : (c4 ? v : tv[4]); ti[4] = c5 ? ti[5] : (c4 ? id : ti[4]);
  tv[5] = c6 ? tv[6] : (c5 ? v : tv[5]); ti[5] = c6 ? ti[6] : (c5 ? id : ti[5]);
  tv[6] = c7 ? tv[7] : (c6 ? v : tv[6]); ti[6] = c7 ? ti[7] : (c6 ? id : ti[6]);
  tv[7] = c7 ? v : tv[7];                ti[7] = c7 ? id : ti[7];
}

// ===== kernel 1: vm (blocks 0..7) + wave-per-tile norm+normalize+staging =====
// One wave = one 16-row tile; lane covers kk=0,1 of its (col,quad) slot.
// Row sumsq reduced with shfl_xor(16,32) across quads -- no LDS, no barrier.
__global__ __launch_bounds__(256) void k_prep(const float* __restrict__ logits,
                                              const float* __restrict__ vf,
                                              const float* __restrict__ pf,
                                              float* __restrict__ vm,
                                              float* __restrict__ inv_vf_s,
                                              float* __restrict__ inv_pf_s,
                                              unsigned short* __restrict__ vfh,
                                              unsigned short* __restrict__ vfl,
                                              unsigned short* __restrict__ pfh,
                                              unsigned short* __restrict__ pfl,
                                              float* __restrict__ out) {
  int bid = blockIdx.x, t = threadIdx.x;
  if (bid < BB) {
    int b = bid;
    __shared__ float smn[4], smx[4];
    float vals[8];
    float mn = 1e30f, mx = -1e30f;
#pragma unroll
    for (int i = 0; i < 8; i++) {
      float x = logits[b * NVV + t + i * 256];
      float s = 1.0f / (1.0f + expf(-x));
      vals[i] = s;
      mn = fminf(mn, s);
      mx = fmaxf(mx, s);
    }
    for (int o = 32; o; o >>= 1) {
      mn = fminf(mn, __shfl_xor(mn, o, 64));
      mx = fmaxf(mx, __shfl_xor(mx, o, 64));
    }
    int w = t >> 6;
    if ((t & 63) == 0) { smn[w] = mn; smx[w] = mx; }
    __syncthreads();
    mn = fminf(fminf(smn[0], smn[1]), fminf(smn[2], smn[3]));
    mx = fmaxf(fmaxf(smx[0], smx[1]), fmaxf(smx[2], smx[3]));
    float range = mx - mn;
#pragma unroll
    for (int i = 0; i < 8; i++) {
      float v = (vals[i] - mn) / range;
      int g = b * NVV + t + i * 256;
      vm[g] = v;
      out[g * 4 + 3] = v;
    }
  } else {
    // 4 tiles per block (one per wave); 3072 tiles total; vf/pf split at
    // tile 1024 (4-aligned -> no block straddles)
    int tile_g = (bid - BB) * 4 + (t >> 6);
    int lane = t & 63, c = lane & 15, quad = (lane >> 4) & 3;
    const float* src;
    unsigned short *dh, *dl;
    float* ginv;
    int tile;
    if (tile_g < QT) { tile = tile_g; src = vf; dh = vfh; dl = vfl; ginv = inv_vf_s; }
    else { tile = tile_g - QT; src = pf; dh = pfh; dl = pfl; ginv = inv_pf_s; }
    int row = tile * 16 + c;
    const float* rp = src + (size_t)row * DD + quad * 8;
    float4 a0 = *(const float4*)(rp);
    float4 b0 = *(const float4*)(rp + 4);
    float4 a1 = *(const float4*)(rp + 32);
    float4 b1 = *(const float4*)(rp + 36);
    float xs[16] = {a0.x, a0.y, a0.z, a0.w, b0.x, b0.y, b0.z, b0.w,
                    a1.x, a1.y, a1.z, a1.w, b1.x, b1.y, b1.z, b1.w};
    float ss = 0.f;
#pragma unroll
    for (int j = 0; j < 16; j++) ss = fmaf(xs[j], xs[j], ss);
    ss += __shfl_xor(ss, 16, 64);
    ss += __shfl_xor(ss, 32, 64);   // all quads now hold the row total
    float inv = 1.0f / fmaxf(sqrtf(ss), 1e-12f);
    if (quad == 0) ginv[row] = 16384.0f * inv;  // pow2 scale: exact ratio later
    ushort8 h, l;
    size_t s0 = (size_t)tile * 128 + lane;      // kk=0 slot
#pragma unroll
    for (int j = 0; j < 8; j++) {
      float xn = xs[j] * inv;
      unsigned short hj = bf16rn(xn);
      h[j] = hj;
      l[j] = bf16rn(xn - bf2f(hj));
    }
    *(ushort8*)(dh + s0 * 8) = h;
    *(ushort8*)(dl + s0 * 8) = l;
#pragma unroll
    for (int j = 0; j < 8; j++) {
      float xn = xs[8 + j] * inv;
      unsigned short hj = bf16rn(xn);
      h[j] = hj;
      l[j] = bf16rn(xn - bf2f(hj));
    }
    *(ushort8*)(dh + (s0 + 64) * 8) = h;      // kk=1 slot
    *(ushort8*)(dl + (s0 + 64) * 8) = l;
  }
}

// ===== kernel 2: MFMA KNN candidate generation (fused KNN1 + KNN2) =====
// Transposed: A = key tile, B = query frags -> lane owns ONE query, 4 keys.
// R14: q-frags pinned in AGPRs ("a" asm) -- MFMA reads A/B from AGPR natively
// (ISA 10), so the home is free and VGPRs are freed for tv/k-frags (R13:
// 177 VALU/tile vs 66 ideal = shuttle bloat). Single chained accumulator
// (saves 4 adds + 4 regs/tile). Merges re-rank exact fp32 (R6); mask is an
// explicit select (R9); insert = branchless med3 net (R8).
__global__ __launch_bounds__(256)
void k_knn(const unsigned short* __restrict__ vfh, const unsigned short* __restrict__ vfl,
           const unsigned short* __restrict__ pfh, const unsigned short* __restrict__ pfl,
           const float* __restrict__ vm,
           unsigned* __restrict__ pc1, unsigned* __restrict__ pc2) {
  int wid = (blockIdx.x * 256 + threadIdx.x) >> 6;
  int lane = threadIdx.x & 63, col = lane & 15, quad = lane >> 4;

  const unsigned short *KH, *KL;
  const float* mask;
  unsigned* PC;
  int qt_g, bt0, row0, ckb, ntiles;
  if (wid < QT * NC1) {  // KNN1: keys = pf, 2 chunks x 128 tiles
    int ck = wid & 1;
    qt_g = wid >> 1;
    int batch = qt_g >> 7;
    KH = pfh; KL = pfl;
    mask = nullptr;
    ntiles = 128;
    bt0 = batch * 256 + ck * 128;
    PC = pc1;
    row0 = ck * 8; ckb = ck * 128;
  } else {               // KNN2: keys = vf, visible only, 2 chunks x 64 tiles
    int w = wid - QT * NC1;
    int ck = w & 1;
    qt_g = w >> 1;
    int batch = qt_g >> 7;
    KH = vfh; KL = vfl;
    mask = vm + batch * NVV;
    ntiles = 64;
    bt0 = batch * 128 + ck * 64;
    PC = pc2;
    row0 = ck * 8; ckb = ck * 64;
  }

  size_t ab = (size_t)qt_g * 1024 + lane * 8;
  short8 qh0 = *(const short8*)(vfh + ab);
  short8 qh1 = *(const short8*)(vfh + ab + 512);
  short8 ql0 = *(const short8*)(vfl + ab);
  short8 ql1 = *(const short8*)(vfl + ab + 512);
  // Pin loop-invariant query frags in AGPRs: free homes (MFMA reads AGPR
  // A/B operands directly), frees 16 VGPRs for tv + key frags.
  asm volatile("" : "+a"(qh0), "+a"(qh1), "+a"(ql0), "+a"(ql1));

  unsigned tv[8];
#pragma unroll
  for (int k = 0; k < 8; k++) tv[k] = 0u;

#pragma unroll 2
  for (int kt = 0; kt < ntiles; kt++) {
    size_t bo = (size_t)(bt0 + kt) * 1024 + lane * 8;
    short8 kh0 = *(const short8*)(KH + bo);
    short8 kh1 = *(const short8*)(KH + bo + 512);
    short8 kl0 = *(const short8*)(KL + bo);
    short8 kl1 = *(const short8*)(KL + bo + 512);
    int base16 = (ckb + kt) * 16;
    f32x4 c = {0.f, 0.f, 0.f, 0.f};
    c = __builtin_amdgcn_mfma_f32_16x16x32_bf16(kh0, qh0, c, 0, 0, 0);
    c = __builtin_amdgcn_mfma_f32_16x16x32_bf16(kh1, qh1, c, 0, 0, 0);
    c = __builtin_amdgcn_mfma_f32_16x16x32_bf16(kh0, ql0, c, 0, 0, 0);
    c = __builtin_amdgcn_mfma_f32_16x16x32_bf16(kh1, ql1, c, 0, 0, 0);
    c = __builtin_amdgcn_mfma_f32_16x16x32_bf16(kl0, qh0, c, 0, 0, 0);
    c = __builtin_amdgcn_mfma_f32_16x16x32_bf16(kl1, qh1, c, 0, 0, 0);
    float4 mv;
    if (mask) mv = *(const float4*)(mask + base16 + quad * 4);
#pragma unroll
    for (int r = 0; r < 4; r++) {
      unsigned u = (unsigned)fmaxf(fmaf(c[r], 520000.0f, 520000.0f), 0.0f);
      unsigned pk = (u << 12) | (unsigned)(base16 + quad * 4 + r);
      if (mask) {
        float mr = (r == 0) ? mv.x : (r == 1) ? mv.y : (r == 2) ? mv.z : mv.w;
        pk = (mr >= 0.5f) ? pk : 0u;
      }
      net8(tv, pk);
    }
  }

  // butterfly across the 4 quads (lane bits 4,5)
#pragma unroll
  for (int m = 16; m <= 32; m <<= 1) {
    unsigned ov[8];
#pragma unroll
    for (int k = 0; k < 8; k++) ov[k] = (unsigned)__shfl_xor((int)tv[k], m, 64);
#pragma unroll
    for (int k = 7; k >= 0; k--) net8(tv, ov[k]);
  }

  if (quad == 0) {
    int q = qt_g * 16 + col;
#pragma unroll
    for (int k = 0; k < 8; k++)
      PC[(size_t)(row0 + k) * NQ + q] = tv[k];
  }
}

__device__ __forceinline__ float dot64(const float4* __restrict__ a,
                                       const float4* __restrict__ b) {
  float a0 = 0.f, a1 = 0.f, a2 = 0.f, a3 = 0.f;
#pragma unroll
  for (int c = 0; c < 16; c++) {
    float4 x = a[c], y = b[c];
    a0 = fmaf(x.x, y.x, a0);
    a1 = fmaf(x.y, y.y, a1);
    a2 = fmaf(x.z, y.z, a2);
    a3 = fmaf(x.w, y.w, a3);
  }
  return (a0 + a1) + (a2 + a3);
}

// ===== kernel 3: exact re-rank of 16 KNN1 candidates + flow_init (16 lanes/q) =====
__global__ __launch_bounds__(256) void k_merge_flow(const unsigned* __restrict__ pc,
                                                    const float* __restrict__ vf,
                                                    const float* __restrict__ pf,
                                                    const float* __restrict__ pts,
                                                    const float* __restrict__ vtx,
                                                    const float* __restrict__ inv_pf_s,
                                                    float* __restrict__ flow_ws,
                                                    float* __restrict__ out) {
  int T = blockIdx.x * 256 + threadIdx.x;
  int q = T >> 4, c = T & 15, batch = q >> 11;
  const float4* qp = (const float4*)(vf + (size_t)q * DD);
  float tv[8];
  int ti[8];
#pragma unroll
  for (int k = 0; k < 8; k++) { tv[k] = -3.0e38f; ti[k] = 0; }
  {  // 16 candidate rows / 16 lanes (KNN1 pk always valid)
    unsigned pk = pc[(size_t)c * NQ + q];
    int id = (int)(pk & 0xFFFu);
    int prow = batch * NPP + id;
    float s = dot64(qp, (const float4*)(pf + (size_t)prow * DD)) *
              inv_pf_s[prow] * 6.103515625e-5f;  // * 2^-14 (exact)
    ins8(tv, ti, s, id);
  }
#pragma unroll
  for (int m = 1; m <= 8; m <<= 1) {
    float ov[8];
    int oi[8];
#pragma unroll
    for (int k = 0; k < 8; k++) {
      ov[k] = __shfl_xor(tv[k], m, 64);
      oi[k] = __shfl_xor(ti[k], m, 64);
    }
#pragma unroll
    for (int k = 7; k >= 0; k--)
      if (ov[k] > tv[0]) ins8(tv, ti, ov[k], oi[k]);
  }
  int id = ti[0];
  float sv = tv[0];
#pragma unroll
  for (int k = 1; k < 8; k++) {
    id = (c == k) ? ti[k] : id;
    sv = (c == k) ? tv[k] : sv;
  }

  float ax = 0.f, ay = 0.f, az = 0.f, den = 0.f;
  if (c < 8) {
    int prow = batch * NPP + id;
    float w = sv * 16384.0f / inv_pf_s[prow];  // = raw dot (exact pow2 ratio)
    ax = (pts[prow * 3 + 0] - vtx[q * 3 + 0]) * w;
    ay = (pts[prow * 3 + 1] - vtx[q * 3 + 1]) * w;
    az = (pts[prow * 3 + 2] - vtx[q * 3 + 2]) * w;
    den = w;
  }
#pragma unroll
  for (int m = 1; m <= 8; m <<= 1) {
    ax += __shfl_xor(ax, m, 64);
    ay += __shfl_xor(ay, m, 64);
    az += __shfl_xor(az, m, 64);
    den += __shfl_xor(den, m, 64);
  }
  if (c == 0) {
    float fx = ax / den, fy = ay / den, fz = az / den;
    flow_ws[q * 4 + 0] = fx;
    flow_ws[q * 4 + 1] = fy;
    flow_ws[q * 4 + 2] = fz;
    out[q * 4 + 0] = fx;
    out[q * 4 + 1] = fy;
    out[q * 4 + 2] = fz;
  }
}

// ===== kernel 4: exact re-rank of 16 KNN2 candidates + interpolate invisible =====
__global__ __launch_bounds__(256) void k_merge_final(const unsigned* __restrict__ pc,
                                                     const float* __restrict__ vf,
                                                     const float* __restrict__ vm,
                                                     const float* __restrict__ inv_vf_s,
                                                     const float* __restrict__ flow_ws,
                                                     float* __restrict__ out) {
  int T = blockIdx.x * 256 + threadIdx.x;
  int q = T >> 4, c = T & 15, batch = q >> 11;
  if (vm[q] >= 0.5f) return;
  const float4* qp = (const float4*)(vf + (size_t)q * DD);
  float tv[8];
  int ti[8];
#pragma unroll
  for (int k = 0; k < 8; k++) { tv[k] = -3.0e38f; ti[k] = 0; }
  {  // pk <= 0xFFF = masked sentinel, skip
    unsigned pk = pc[(size_t)c * NQ + q];
    if (pk > 0xFFFu) {
      int id = (int)(pk & 0xFFFu);
      int krow = batch * NVV + id;
      float s = dot64(qp, (const float4*)(vf + (size_t)krow * DD)) *
                inv_vf_s[krow] * 6.103515625e-5f;
      ins8(tv, ti, s, id);
    }
  }
#pragma unroll
  for (int m = 1; m <= 8; m <<= 1) {
    float ov[8];
    int oi[8];
#pragma unroll
    for (int k = 0; k < 8; k++) {
      ov[k] = __shfl_xor(tv[k], m, 64);
      oi[k] = __shfl_xor(ti[k], m, 64);
    }
#pragma unroll
    for (int k = 7; k >= 0; k--)
      if (ov[k] > tv[0]) ins8(tv, ti, ov[k], oi[k]);
  }
  int id = ti[0];
  float sv = tv[0];
#pragma unroll
  for (int k = 1; k < 8; k++) {
    id = (c == k) ? ti[k] : id;
    sv = (c == k) ? tv[k] : sv;
  }

  float ax = 0.f, ay = 0.f, az = 0.f, den = 0.f;
  if (c < 8) {
    int krow = batch * NVV + id;
    float w = sv * 16384.0f / inv_vf_s[krow];
    ax = flow_ws[krow * 4 + 0] * w;
    ay = flow_ws[krow * 4 + 1] * w;
    az = flow_ws[krow * 4 + 2] * w;
    den = w;
  }
#pragma unroll
  for (int m = 1; m <= 8; m <<= 1) {
    ax += __shfl_xor(ax, m, 64);
    ay += __shfl_xor(ay, m, 64);
    az += __shfl_xor(az, m, 64);
    den += __shfl_xor(den, m, 64);
  }
  if (c == 0) {
    out[q * 4 + 0] = ax / den;
    out[q * 4 + 1] = ay / den;
    out[q * 4 + 2] = az / den;
  }
}

extern "C" void kernel_launch(void* const* d_in, const int* in_sizes, int n_in,
                              void* d_out, int out_size, void* d_ws, size_t ws_size,
                              hipStream_t stream) {
  const float* vtx = (const float*)d_in[0];
  const float* pts = (const float*)d_in[1];
  const float* vf = (const float*)d_in[2];
  const float* pf = (const float*)d_in[3];
  const float* lg = (const float*)d_in[4];
  float* out = (float*)d_out;
  float* ws = (float*)d_ws;

  float* vm = ws;
  float* inv_vf_s = ws + 16384;
  float* inv_pf_s = ws + 32768;
  float* flow = ws + 65536;
  unsigned* pc1 = (unsigned*)(ws + 131072);
  unsigned* pc2 = (unsigned*)(ws + 393216);
  unsigned short* vfh = (unsigned short*)(ws + 655360);
  unsigned short* vfl = (unsigned short*)(ws + 1179648);   // +524288 floats
  unsigned short* pfh = (unsigned short*)(ws + 1703936);   // +524288
  unsigned short* pfl = (unsigned short*)(ws + 2752512);   // +1048576

  k_prep<<<BB + 768, 256, 0, stream>>>(lg, vf, pf, vm, inv_vf_s, inv_pf_s,
                                       vfh, vfl, pfh, pfl, out);
  k_knn<<<(QT * NC1 + QT * NC2) / 4, 256, 0, stream>>>(vfh, vfl, pfh, pfl,
                                                       vm, pc1, pc2);
  k_merge_flow<<<NQ * 16 / 256, 256, 0, stream>>>(pc1, vf, pf, pts, vtx,
                                                  inv_pf_s, flow, out);
  k_merge_final<<<NQ * 16 / 256, 256, 0, stream>>>(pc2, vf, vm, inv_vf_s, flow, out);
}